// Round 6
// baseline (41.764 us; speedup 1.0000x reference)
//
#include <hip/hip_runtime.h>
#include <stdint.h>

#define SCAN_BS 1024
#define OBJ_BS  256
#define SLAB_F  (OBJ_BS * 21)     // 5376 floats = 21504 B
#define SLAB_CH (SLAB_F / 256)    // 21 wave-chunks (64 lanes x 16 B)

// ---- global->LDS DMA helper (size must be a literal) ----
__device__ __forceinline__ void gload_lds16(const void* g, void* l) {
    __builtin_amdgcn_global_load_lds(
        (const __attribute__((address_space(1))) uint32_t*)g,
        (__attribute__((address_space(3))) uint32_t*)l, 16, 0, 0);
}

// ---------------- fused scan + cav-index materialization (ONE kernel) ----------------
// Each block redundantly computes carry = sum(counts[0..chunkStart)) via coalesced
// strided loads (L2-resident, ~15 MB total redundancy = free), block-scans its chunk,
// then scatter-writes cavIdx[start..end) = cav. No inter-block communication.

__global__ __launch_bounds__(SCAN_BS) void scan_scatter_kernel(
    const int* __restrict__ counts, int C,
    int* __restrict__ cavIdx) {

    __shared__ int sdata[SCAN_BS];
    __shared__ int wsum[SCAN_BS / 64];

    const int tid  = threadIdx.x;
    const int lane = tid & 63;
    const int wid  = tid >> 6;
    const int b    = blockIdx.x;
    const int gid  = b * SCAN_BS + tid;
    const int chunkStart = b * SCAN_BS;

    const int v = (gid < C) ? counts[gid] : 0;
    sdata[tid] = v;

    // redundant carry: strided coalesced sum of all preceding counts
    int csum = 0;
    for (int idx = tid; idx < chunkStart; idx += SCAN_BS) csum += counts[idx];
    #pragma unroll
    for (int o = 32; o > 0; o >>= 1) csum += __shfl_down(csum, o, 64);
    if (lane == 0) wsum[wid] = csum;
    __syncthreads();

    // Hillis-Steele inclusive scan of the chunk
    for (int ofs = 1; ofs < SCAN_BS; ofs <<= 1) {
        int add = (tid >= ofs) ? sdata[tid - ofs] : 0;
        __syncthreads();
        sdata[tid] += add;
        __syncthreads();
    }

    int carry = 0;
    #pragma unroll
    for (int w = 0; w < SCAN_BS / 64; ++w) carry += wsum[w];

    if (gid < C) {
        const int end   = sdata[tid] + carry;   // inclusive cumsum
        const int start = end - v;
        // contiguous overall: thread g's range abuts thread g+1's
        for (int s = start; s < end; ++s) cavIdx[s] = gid;
    }
}

// ---------------- main per-object kernel ----------------
//
// out layout (floats):
//   [0,       8N)  obj_input  [1,N,2,4]
//   [8N,     10N)  query      [1,N,1,2]
//   [10N,    12N)  time_encode[N,2]
//   [12N,    13N)  target_time_diff [N]

__global__ __launch_bounds__(OBJ_BS) void motion_kernel(
    const float* __restrict__ bbx, const float* __restrict__ tint,
    const int* __restrict__ cavIdx, int N,
    float* __restrict__ out) {

    __shared__ __align__(16) float sb[SLAB_F];   // 21504 B -> 7 blocks/CU

    const int tid  = threadIdx.x;
    const int lane = tid & 63;
    const int wid  = tid >> 6;
    const long long blockStart = (long long)blockIdx.x * OBJ_BS;
    const int nObjBlk = (int)min((long long)OBJ_BS, (long long)N - blockStart);

    // ---- bbx slab DMA: fire-and-forget, addresses depend only on blockIdx ----
    const float* gsrc = bbx + blockStart * 21;
    if (nObjBlk == OBJ_BS) {
        #pragma unroll
        for (int ch = wid; ch < SLAB_CH; ch += 4)
            gload_lds16((const void*)(gsrc + ch * 256 + lane * 4), (void*)(sb + ch * 256));
    } else {
        // tail fallback (not hit when N % 256 == 0)
        const int nElem = nObjBlk * 21;
        for (int k = tid; k < nElem; k += OBJ_BS) sb[k] = gsrc[k];
    }

    const int i = (int)(blockStart + tid);
    const bool act = (tid < nObjBlk);

    // coalesced per-thread cav id; tint gathers issue during the DMA drain
    const int   cav = act ? cavIdx[i] : 0;
    const float t0  = tint[3 * cav + 0];
    const float t1  = tint[3 * cav + 1];
    const float t2  = tint[3 * cav + 2];

    __syncthreads();   // drains bbx DMA

    if (!act) return;

    // td_rep = [t2, t1, t0];  dt = time_encode
    const float dt0 = t1 - t2;
    const float dt1 = t0 - t1;

    // frames from LDS: frame k at sb[tid*21 + k*7 + {0,1}] (stride 21 -> conflict-free)
    const float* bp = sb + tid * 21;
    const float x0 = bp[0],  y0 = bp[1];
    const float x1 = bp[7],  y1 = bp[8];
    const float x2 = bp[14], y2 = bp[15];

    // coords (flipped, normalized to last): c0v = f2-f0, c1v = f1-f0, c2v = 0
    const float c0x = x2 - x0, c0y = y2 - y0;
    const float c1x = x1 - x0, c1y = y1 - y0;

    const float d0x = c1x - c0x, d0y = c1y - c0y;
    const float d1x = 0.0f - c1x, d1y = 0.0f - c1y;

    const float s0x = d0x / dt0, s0y = d0y / dt0;
    const float s1x = d1x / dt1, s1y = d1y / dt1;

    const float last_len = 0.0f - (t1 - t0);
    const float safe_len = (last_len == 0.0f) ? 1.0f : last_len;
    const float exx = ((0.0f - c1x) * (0.0f - t0)) / safe_len;
    const float exy = ((0.0f - c1y) * (0.0f - t0)) / safe_len;
    const float qx = (last_len == 0.0f) ? 0.0f : exx;
    const float qy = (last_len == 0.0f) ? 0.0f : exy;

    // ---- writes (all coalesced) ----
    const size_t Ns = (size_t)N;
    float4* oi = (float4*)out;
    oi[(size_t)i * 2 + 0] = make_float4(d0x, d0y, s0x, s0y);
    oi[(size_t)i * 2 + 1] = make_float4(d1x, d1y, s1x, s1y);

    float2* q  = (float2*)(out + 8 * Ns);
    q[i] = make_float2(qx, qy);

    float2* te = (float2*)(out + 10 * Ns);
    te[i] = make_float2(dt0, dt1);

    out[12 * Ns + (size_t)i] = 0.0f - t0;
}

// ---------------- launch ----------------

extern "C" void kernel_launch(void* const* d_in, const int* in_sizes, int n_in,
                              void* d_out, int out_size, void* d_ws, size_t ws_size,
                              hipStream_t stream) {
    const float* bbx  = (const float*)d_in[0];   // [N,3,7]
    const float* tint = (const float*)d_in[1];   // [C*3]
    const int*   cnt  = (const int*)d_in[2];     // [C]
    float* out = (float*)d_out;

    const int N = in_sizes[0] / 21;
    const int C = in_sizes[2];

    const int nb  = (C + SCAN_BS - 1) / SCAN_BS;
    const int nob = (N + OBJ_BS - 1) / OBJ_BS;

    int* cavIdx = (int*)d_ws;                    // N ints (~4 MB)

    scan_scatter_kernel<<<nb, SCAN_BS, 0, stream>>>(cnt, C, cavIdx);
    motion_kernel<<<nob, OBJ_BS, 0, stream>>>(bbx, tint, cavIdx, N, out);
}